// Round 2
// baseline (231.078 us; speedup 1.0000x reference)
//
#include <hip/hip_runtime.h>
#include <hip/hip_bf16.h>
#include <math.h>

#define PI_D 3.14159265358979323846
#define NLAT 128
#define NLON 256
#define LMAX 50
#define MMAX 50
#define NPTS 2048
#define NFIELD 4   // {pred,target} x {b0,b1}
#define MGRID (NLAT * NLON)

// ---------------------------------------------------------------------------
// Kernel A: Legendre * quadrature-weight table PCTW[m][l][k], double precision.
// grid: 50 blocks (m), 128 threads (k). Uniform-per-block coefficients staged
// in LDS; CC weight sum via Chebyshev recurrence (no per-term double cos).
// ---------------------------------------------------------------------------
__global__ __launch_bounds__(128) void precompute_pctw(float* __restrict__ pctw) {
    int k = threadIdx.x;   // 0..127 (latitude node)
    int m = blockIdx.x;    // 0..49

    __shared__ double sa[LMAX], sb[LMAX], sc[LMAX];
    if (k < LMAX) {
        int l = k;
        double av = 0.0, bv = 0.0;
        if (l >= m + 2) {
            double ll = (double)l;
            double denom = ll * ll - (double)(m * m);
            av = sqrt((4.0 * ll * ll - 1.0) / denom);
            bv = sqrt(((2.0 * ll + 1.0) * (double)(l - 1 + m) * (double)(l - 1 - m)) /
                      ((2.0 * ll - 3.0) * denom));
        }
        sa[l] = av;
        sb[l] = bv;
        // pmm step factor sqrt((2i+1)/(2i)) for i=1..49 (index i stored at sc[i])
        sc[l] = (l >= 1) ? sqrt((2.0 * (double)l + 1.0) / (2.0 * (double)l)) : 0.0;
    }
    __syncthreads();

    double theta = PI_D * (double)k / 127.0;
    double cost = cos(theta);
    double sint = sqrt(fmax(1.0 - cost * cost, 0.0));

    // Clenshaw-Curtis weight (Nn = 127, odd -> all b = 2.0).
    // cos(2 t theta) via Chebyshev recurrence.
    double c2 = cos(2.0 * theta);
    double two_c2 = 2.0 * c2;
    double cp = 1.0, cc = c2;
    double v = 0.0;
    for (int t = 1; t <= 63; ++t) {
        v += 2.0 * cc / (double)(4 * t * t - 1);
        double cn = two_c2 * cc - cp;
        cp = cc;
        cc = cn;
    }
    double w = (2.0 / 127.0) * (1.0 - v);
    if (k == 0 || k == 127) w *= 0.5;

    // pmm recurrence up to order m (factors from LDS)
    double pmm = sqrt(1.0 / (4.0 * PI_D));
    for (int i = 1; i <= m; ++i)
        pmm = -pmm * sc[i] * sint;

    float* out = pctw + (m * LMAX) * NLAT + k;  // [m][l][k], stride NLAT per l
    for (int l = 0; l < m; ++l) out[l * NLAT] = 0.0f;

    out[m * NLAT] = (float)(pmm * w);
    double plm2 = pmm, plm1 = 0.0;
    if (m + 1 < LMAX) {
        plm1 = sqrt(2.0 * (double)m + 3.0) * cost * pmm;
        out[(m + 1) * NLAT] = (float)(plm1 * w);
    }
    for (int l = m + 2; l < LMAX; ++l) {
        double p = sa[l] * cost * plm1 - sb[l] * plm2;
        out[l * NLAT] = (float)(p * w);
        plm2 = plm1;
        plm1 = p;
    }
}

// ---------------------------------------------------------------------------
// Kernel B: to_spherical for all 4 fields. sph[f][n] = (theta, az-pi, r, pad)
// ---------------------------------------------------------------------------
__global__ void to_sph(const float* __restrict__ pred, const float* __restrict__ tgt,
                       float* __restrict__ sph) {
    int idx = blockIdx.x * blockDim.x + threadIdx.x;  // 0..8191
    if (idx >= NFIELD * NPTS) return;
    int f = idx >> 11;   // 0..3
    int n = idx & (NPTS - 1);
    const float* src = ((f < 2) ? pred : tgt) + ((size_t)(f & 1) * NPTS + n) * 3;
    float x = src[0], y = src[1], z = src[2];
    // match reference summation order: flip-cumsum-flip
    float s1 = z * z;
    float s2 = s1 + y * y;
    float s3 = s2 + x * x;
    float r = sqrtf(s3);
    float rho = sqrtf(s2);
    float theta = acosf(x / r);
    float a = acosf(y / rho);
    float az = (z < 0.0f) ? (a + (2.0f * (float)PI_D - 2.0f * a)) : a;
    az -= (float)PI_D;
    float4* dst = (float4*)(sph + (size_t)idx * 4);
    *dst = make_float4(theta, az, r, 0.0f);
}

// ---------------------------------------------------------------------------
// Kernel C: brute-force 3-NN + distance-weighted interp onto the grid.
// v2: each thread handles TWO grid points (adjacent lats, same lon) ->
// shared dl^2 and amortized LDS reads; early-out branch around the top-3
// insert (rarely taken after warm-up); float4 LDS reads (broadcast).
// grid: (64 lat-pairs, 4 fields) blocks, 256 threads (= lon).
// ---------------------------------------------------------------------------
#define KNN_INSERT(d, n, k0, k1, k2, i0, i1, i2)          \
    if ((d) < (k2)) {                                      \
        bool c0 = (d) < (k0), c1 = (d) < (k1);             \
        (k2) = c1 ? (k1) : (d); (i2) = c1 ? (i1) : (n);    \
        float nk = c0 ? (k0) : (d); int ni = c0 ? (i0) : (n); \
        (k1) = c1 ? nk : (k1); (i1) = c1 ? ni : (i1);      \
        (k0) = c0 ? (d) : (k0); (i0) = c0 ? (n) : (i0);    \
    }

__global__ __launch_bounds__(256) void knn_interp(const float* __restrict__ sph,
                                                  float* __restrict__ gridf) {
    __shared__ float4 s_t4[NPTS / 4];
    __shared__ float4 s_l4[NPTS / 4];
    __shared__ float s_r[NPTS];

    int f = blockIdx.y;
    const float4* base = (const float4*)(sph + (size_t)f * NPTS * 4);
    float* st = (float*)s_t4;
    float* sl = (float*)s_l4;
    for (int n = threadIdx.x; n < NPTS; n += 256) {
        float4 p = base[n];
        st[n] = p.x;
        sl[n] = p.y;
        s_r[n] = p.z;
    }
    __syncthreads();

    int j = threadIdx.x;           // lon
    int lat0 = blockIdx.x * 2;     // lat pair
    float gl = (float)(((double)j - 128.0) * PI_D / 128.0);
    float gt0 = (float)((double)lat0 * PI_D / 128.0);
    float gt1 = (float)((double)(lat0 + 1) * PI_D / 128.0);

    float k0a = 1e30f, k1a = 1e30f, k2a = 1e30f;
    float k0b = 1e30f, k1b = 1e30f, k2b = 1e30f;
    int i0a = 0, i1a = 0, i2a = 0;
    int i0b = 0, i1b = 0, i2b = 0;

#pragma unroll 2
    for (int c = 0; c < NPTS / 4; ++c) {
        float4 tv = s_t4[c];
        float4 lv = s_l4[c];
        int nb = c * 4;
        {
            float dl = gl - lv.x; float dl2 = dl * dl;
            float dt = gt0 - tv.x; float d = fmaf(dt, dt, dl2);
            KNN_INSERT(d, nb + 0, k0a, k1a, k2a, i0a, i1a, i2a)
            float dtb = gt1 - tv.x; float db = fmaf(dtb, dtb, dl2);
            KNN_INSERT(db, nb + 0, k0b, k1b, k2b, i0b, i1b, i2b)
        }
        {
            float dl = gl - lv.y; float dl2 = dl * dl;
            float dt = gt0 - tv.y; float d = fmaf(dt, dt, dl2);
            KNN_INSERT(d, nb + 1, k0a, k1a, k2a, i0a, i1a, i2a)
            float dtb = gt1 - tv.y; float db = fmaf(dtb, dtb, dl2);
            KNN_INSERT(db, nb + 1, k0b, k1b, k2b, i0b, i1b, i2b)
        }
        {
            float dl = gl - lv.z; float dl2 = dl * dl;
            float dt = gt0 - tv.z; float d = fmaf(dt, dt, dl2);
            KNN_INSERT(d, nb + 2, k0a, k1a, k2a, i0a, i1a, i2a)
            float dtb = gt1 - tv.z; float db = fmaf(dtb, dtb, dl2);
            KNN_INSERT(db, nb + 2, k0b, k1b, k2b, i0b, i1b, i2b)
        }
        {
            float dl = gl - lv.w; float dl2 = dl * dl;
            float dt = gt0 - tv.w; float d = fmaf(dt, dt, dl2);
            KNN_INSERT(d, nb + 3, k0a, k1a, k2a, i0a, i1a, i2a)
            float dtb = gt1 - tv.w; float db = fmaf(dtb, dtb, dl2);
            KNN_INSERT(db, nb + 3, k0b, k1b, k2b, i0b, i1b, i2b)
        }
    }

    // weights = d_k / sum(d_k); k0..k2 already hold the selected distances
    {
        float r0 = s_r[i0a], r1 = s_r[i1a], r2 = s_r[i2a];
        float s = k0a + k1a + k2a;
        gridf[(size_t)f * MGRID + lat0 * NLON + j] =
            (k0a * r0 + k1a * r1 + k2a * r2) / s;
    }
    {
        float r0 = s_r[i0b], r1 = s_r[i1b], r2 = s_r[i2b];
        float s = k0b + k1b + k2b;
        gridf[(size_t)f * MGRID + (lat0 + 1) * NLON + j] =
            (k0b * r0 + k1b * r1 + k2b * r2) / s;
    }
}

// ---------------------------------------------------------------------------
// Kernel D: real part of rfft * (2*pi/NLON), first MMAX modes.
// One 64-thread block per (f,k) row; row + twiddles staged in LDS.
// ---------------------------------------------------------------------------
__global__ __launch_bounds__(64) void dft_cos(const float* __restrict__ gridf,
                                              float* __restrict__ fre) {
    __shared__ float row[NLON];
    __shared__ float ctab[NLON];
    int fk = blockIdx.x;  // 0..511 (f*NLAT + k)
    int t = threadIdx.x;

    ((float4*)row)[t] = ((const float4*)(gridf + (size_t)fk * NLON))[t];
    for (int i = t; i < NLON; i += 64)
        ctab[i] = (float)cos(2.0 * PI_D * (double)i / (double)NLON);
    __syncthreads();

    if (t < MMAX) {
        float acc = 0.0f;
        int p = 0;
        for (int jj = 0; jj < NLON; ++jj) {
            acc += row[jj] * ctab[p];
            p = (p + t) & (NLON - 1);
        }
        fre[fk * MMAX + t] = acc * (float)(2.0 * PI_D / (double)NLON);
    }
}

// ---------------------------------------------------------------------------
// Kernel E: Legendre contraction + squared-diff loss with RECTW weighting.
// One 64-thread block per (b,l); thread = mm. Wave-reduce, one atomic/block.
// ---------------------------------------------------------------------------
__global__ __launch_bounds__(64) void contract_loss(const float* __restrict__ fre,
                                                    const float* __restrict__ pctw,
                                                    float* __restrict__ out) {
    int b = blockIdx.x / LMAX;   // 0..1
    int l = blockIdx.x % LMAX;   // 0..49
    int mm = threadIdx.x;        // 0..63 (50 active)
    float contrib = 0.0f;
    if (mm < MMAX) {
        const float* pw = pctw + (size_t)(mm * LMAX + l) * NLAT;
        const float* fp = fre + (size_t)b * NLAT * MMAX + mm;
        const float* ft = fre + (size_t)(2 + b) * NLAT * MMAX + mm;
        float pc = 0.0f, tc = 0.0f;
#pragma unroll 8
        for (int k = 0; k < NLAT; ++k) {
            float w = pw[k];
            pc += fp[k * MMAX] * w;
            tc += ft[k * MMAX] * w;
        }
        float diff = pc - tc;
        double dl_ = (double)(49 - l);
        float rw = (float)exp(-(dl_ * dl_) / 5000.0);
        contrib = diff * diff * rw * 0.5f;  // 0.5 = mean over batch of 2
    }
    for (int off = 32; off > 0; off >>= 1) contrib += __shfl_down(contrib, off);
    if (threadIdx.x == 0) atomicAdd(out, contrib);
}

// ---------------------------------------------------------------------------
extern "C" void kernel_launch(void* const* d_in, const int* in_sizes, int n_in,
                              void* d_out, int out_size, void* d_ws, size_t ws_size,
                              hipStream_t stream) {
    const float* pred = (const float*)d_in[0];
    const float* tgt = (const float*)d_in[1];
    float* ws = (float*)d_ws;

    // ws layout (floats):
    float* pctw  = ws;                            // 50*50*128 = 320000
    float* sph   = ws + 320000;                   // 4*2048*4  =  32768
    float* gridf = ws + 320000 + 32768;           // 4*32768   = 131072
    float* fre   = ws + 320000 + 32768 + 131072;  // 4*128*50  =  25600
    float* out = (float*)d_out;

    hipMemsetAsync(out, 0, sizeof(float), stream);

    precompute_pctw<<<LMAX, NLAT, 0, stream>>>(pctw);
    to_sph<<<(NFIELD * NPTS + 255) / 256, 256, 0, stream>>>(pred, tgt, sph);
    knn_interp<<<dim3(NLAT / 2 / 1, NFIELD), 256, 0, stream>>>(sph, gridf);  // 64 x 4 blocks
    dft_cos<<<NFIELD * NLAT, 64, 0, stream>>>(gridf, fre);
    contract_loss<<<2 * LMAX, 64, 0, stream>>>(fre, pctw, out);
}

// Round 3
// 131.663 us; speedup vs baseline: 1.7551x; 1.7551x over previous
//
#include <hip/hip_runtime.h>
#include <hip/hip_bf16.h>
#include <math.h>

#define PI_D 3.14159265358979323846
#define NLAT 128
#define NLON 256
#define LMAX 50
#define MMAX 50
#define NPTS 2048
#define NFIELD 4   // {pred,target} x {b0,b1}
#define MGRID (NLAT * NLON)

__device__ __forceinline__ unsigned umin_(unsigned a, unsigned b) { return a < b ? a : b; }
__device__ __forceinline__ unsigned umax_(unsigned a, unsigned b) { return a > b ? a : b; }

// ---------------------------------------------------------------------------
// Kernel 1 (fused): blocks 0..511  = knn+interp+DFT, one (field, lat-row) each
//                   blocks 512..561 = PCTW table (m = bid-512); block 512 also
//                   zeroes out[0] for kernel 2's atomics.
// ---------------------------------------------------------------------------
__global__ __launch_bounds__(256) void fused_main(
    const float* __restrict__ pred, const float* __restrict__ tgt,
    float* __restrict__ pctw, float* __restrict__ fre, float* __restrict__ out) {

    // knn-role LDS
    __shared__ float2 s_tl[NPTS];    // (theta, az-pi) per candidate  16 KB
    __shared__ float  s_r[NPTS];     // radius                          8 KB
    __shared__ float  ctab[NLON];    // DFT twiddles                    1 KB
    __shared__ float  row[NLON];     // interpolated lat row            1 KB
    __shared__ float  part[MMAX * 4];
    // pctw-role LDS
    __shared__ double sa[LMAX], sb[LMAX], sc[LMAX];

    int bid = blockIdx.x;
    int t = threadIdx.x;

    if (bid >= 512) {
        // ---------------- PCTW role ----------------
        int m = bid - 512;           // 0..49
        if (m == 0 && t == 0) out[0] = 0.0f;  // zero-init for contract's atomics
        if (t < LMAX) {
            int l = t;
            double av = 0.0, bv = 0.0;
            if (l >= m + 2) {
                double ll = (double)l;
                double denom = ll * ll - (double)(m * m);
                av = sqrt((4.0 * ll * ll - 1.0) / denom);
                bv = sqrt(((2.0 * ll + 1.0) * (double)(l - 1 + m) * (double)(l - 1 - m)) /
                          ((2.0 * ll - 3.0) * denom));
            }
            sa[l] = av;
            sb[l] = bv;
            sc[l] = (l >= 1) ? sqrt((2.0 * (double)l + 1.0) / (2.0 * (double)l)) : 0.0;
        }
        __syncthreads();
        if (t < NLAT) {
            int k = t;
            double theta = PI_D * (double)k / 127.0;
            double cost = cos(theta);
            double sint = sqrt(fmax(1.0 - cost * cost, 0.0));
            // Clenshaw-Curtis weight via Chebyshev recurrence (Nn=127, odd)
            double c2 = cos(2.0 * theta);
            double two_c2 = 2.0 * c2;
            double cp = 1.0, cc = c2, v = 0.0;
            for (int tt = 1; tt <= 63; ++tt) {
                v += 2.0 * cc / (double)(4 * tt * tt - 1);
                double cn = two_c2 * cc - cp;
                cp = cc;
                cc = cn;
            }
            double w = (2.0 / 127.0) * (1.0 - v);
            if (k == 0 || k == 127) w *= 0.5;

            double pmm = sqrt(1.0 / (4.0 * PI_D));
            for (int i = 1; i <= m; ++i) pmm = -pmm * sc[i] * sint;

            float* o = pctw + (m * LMAX) * NLAT + k;
            for (int l = 0; l < m; ++l) o[l * NLAT] = 0.0f;
            o[m * NLAT] = (float)(pmm * w);
            double plm2 = pmm, plm1 = 0.0;
            if (m + 1 < LMAX) {
                plm1 = sqrt(2.0 * (double)m + 3.0) * cost * pmm;
                o[(m + 1) * NLAT] = (float)(plm1 * w);
            }
            for (int l = m + 2; l < LMAX; ++l) {
                double p = sa[l] * cost * plm1 - sb[l] * plm2;
                o[l * NLAT] = (float)(p * w);
                plm2 = plm1;
                plm1 = p;
            }
        }
        return;
    }

    // ---------------- KNN + interp + DFT role ----------------
    int f = bid >> 7;         // 0..3: {pred b0, pred b1, tgt b0, tgt b1}
    int lat = bid & 127;      // lat row
    const float* src = ((f < 2) ? pred : tgt) + (size_t)(f & 1) * NPTS * 3;

    // inline to_spherical, staged into LDS (exact same fp order as reference)
    for (int n = t; n < NPTS; n += 256) {
        float x = src[3 * n], y = src[3 * n + 1], z = src[3 * n + 2];
        float s1 = z * z;
        float s2 = s1 + y * y;
        float s3 = s2 + x * x;
        float r = sqrtf(s3);
        float rho = sqrtf(s2);
        float theta = acosf(x / r);
        float a = acosf(y / rho);
        float az = (z < 0.0f) ? (a + (2.0f * (float)PI_D - 2.0f * a)) : a;
        az -= (float)PI_D;
        s_tl[n] = make_float2(theta, az);
        s_r[n] = r;
    }
    ctab[t] = (float)cos(2.0 * PI_D * (double)t / (double)NLON);
    __syncthreads();

    int j = t;  // lon
    float gl = (float)(((double)j - 128.0) * PI_D / 128.0);
    float gt = (float)((double)lat * PI_D / 128.0);

    // branchless top-3 on packed keys: high 21 bits = distance, low 11 = index
    unsigned k0 = 0xFFFFFFFFu, k1 = 0xFFFFFFFFu, k2 = 0xFFFFFFFFu;
    const float4* tl4 = (const float4*)s_tl;
#pragma unroll 4
    for (int c = 0; c < NPTS / 2; ++c) {
        float4 v = tl4[c];  // candidates 2c (v.x,v.y) and 2c+1 (v.z,v.w)
        {
            float dt = gt - v.x, dl = gl - v.y;
            float d = fmaf(dt, dt, dl * dl);
            unsigned key = (__float_as_uint(d) & 0xFFFFF800u) | (unsigned)(2 * c);
            unsigned nk2 = umin_(umax_(key, k1), k2);   // med3(key,k1,k2)
            unsigned nk1 = umin_(umax_(key, k0), k1);   // med3(key,k0,k1)
            k0 = umin_(key, k0);
            k1 = nk1;
            k2 = nk2;
        }
        {
            float dt = gt - v.z, dl = gl - v.w;
            float d = fmaf(dt, dt, dl * dl);
            unsigned key = (__float_as_uint(d) & 0xFFFFF800u) | (unsigned)(2 * c + 1);
            unsigned nk2 = umin_(umax_(key, k1), k2);
            unsigned nk1 = umin_(umax_(key, k0), k1);
            k0 = umin_(key, k0);
            k1 = nk1;
            k2 = nk2;
        }
    }

    // epilogue: recover indices, recompute EXACT distances, interp weights
    {
        int i0 = k0 & 0x7FF, i1 = k1 & 0x7FF, i2 = k2 & 0x7FF;
        float2 p0 = s_tl[i0], p1 = s_tl[i1], p2 = s_tl[i2];
        float dt0 = gt - p0.x, dl0 = gl - p0.y;
        float dt1 = gt - p1.x, dl1 = gl - p1.y;
        float dt2 = gt - p2.x, dl2 = gl - p2.y;
        float d0 = fmaf(dt0, dt0, dl0 * dl0);
        float d1 = fmaf(dt1, dt1, dl1 * dl1);
        float d2 = fmaf(dt2, dt2, dl2 * dl2);
        float s = d0 + d1 + d2;
        row[j] = (d0 * s_r[i0] + d1 * s_r[i1] + d2 * s_r[i2]) / s;
    }
    __syncthreads();

    // DFT of the row: 50 modes x 4 partial sums (threads 0..199), then combine
    if (t < MMAX * 4) {
        int mm = t >> 2, q = t & 3;
        int base = q * 64;
        float acc = 0.0f;
        int p = (base * mm) & (NLON - 1);
        for (int i = 0; i < 64; ++i) {
            acc += row[base + i] * ctab[p];
            p = (p + mm) & (NLON - 1);
        }
        part[t] = acc;
    }
    __syncthreads();
    if (t < MMAX) {
        float v = ((part[4 * t] + part[4 * t + 1]) + (part[4 * t + 2] + part[4 * t + 3])) *
                  (float)(2.0 * PI_D / (double)NLON);
        fre[(f * NLAT + lat) * MMAX + t] = v;
    }
}

// ---------------------------------------------------------------------------
// Kernel 2: Legendre contraction + squared-diff loss with RECTW weighting.
// One 64-thread block per (b,l); thread = mm. Wave-reduce, one atomic/block.
// out[0] was zeroed by kernel 1.
// ---------------------------------------------------------------------------
__global__ __launch_bounds__(64) void contract_loss(const float* __restrict__ fre,
                                                    const float* __restrict__ pctw,
                                                    float* __restrict__ out) {
    int b = blockIdx.x / LMAX;   // 0..1
    int l = blockIdx.x % LMAX;   // 0..49
    int mm = threadIdx.x;        // 0..63 (50 active)
    float contrib = 0.0f;
    if (mm < MMAX) {
        const float* pw = pctw + (size_t)(mm * LMAX + l) * NLAT;
        const float* fp = fre + (size_t)b * NLAT * MMAX + mm;
        const float* ft = fre + (size_t)(2 + b) * NLAT * MMAX + mm;
        float pc = 0.0f, tc = 0.0f;
#pragma unroll 8
        for (int k = 0; k < NLAT; ++k) {
            float w = pw[k];
            pc += fp[k * MMAX] * w;
            tc += ft[k * MMAX] * w;
        }
        float diff = pc - tc;
        double dl_ = (double)(49 - l);
        float rw = (float)exp(-(dl_ * dl_) / 5000.0);
        contrib = diff * diff * rw * 0.5f;  // 0.5 = mean over batch of 2
    }
    for (int off = 32; off > 0; off >>= 1) contrib += __shfl_down(contrib, off);
    if (threadIdx.x == 0) atomicAdd(out, contrib);
}

// ---------------------------------------------------------------------------
extern "C" void kernel_launch(void* const* d_in, const int* in_sizes, int n_in,
                              void* d_out, int out_size, void* d_ws, size_t ws_size,
                              hipStream_t stream) {
    const float* pred = (const float*)d_in[0];
    const float* tgt = (const float*)d_in[1];
    float* ws = (float*)d_ws;

    // ws layout (floats):
    float* pctw = ws;                 // 50*50*128 = 320000
    float* fre  = ws + 320000;        // 4*128*50  =  25600
    float* out = (float*)d_out;

    fused_main<<<562, 256, 0, stream>>>(pred, tgt, pctw, fre, out);
    contract_loss<<<2 * LMAX, 64, 0, stream>>>(fre, pctw, out);
}